// Round 1
// baseline (381.924 us; speedup 1.0000x reference)
//
#include <hip/hip_runtime.h>
#include <hip/hip_bf16.h>
#include <hip/hip_fp16.h>
#include <math.h>

#define DEV_INLINE __device__ __forceinline__

typedef __attribute__((ext_vector_type(8))) short short8;
typedef __attribute__((ext_vector_type(8))) unsigned short ushort8v;
typedef __attribute__((ext_vector_type(4))) float f32x4;

constexpr int H = 128, W = 128, C = 128, B = 4;
constexpr int KK = 9;
constexpr int KT2 = 1184;         // 37 chunks * 32

DEV_INLINE unsigned short f2bf(float f) {
  union { float f; unsigned u; } v; v.f = f;
  unsigned r = v.u + 0x7FFFu + ((v.u >> 16) & 1u);   // RNE
  return (unsigned short)(r >> 16);
}
DEV_INLINE float ubits(unsigned u) {
  union { unsigned u; float f; } v; v.u = u; return v.f;
}
DEV_INLINE float bfu(unsigned short u) { return ubits(((unsigned)u) << 16); }
DEV_INLINE unsigned pack2bf(float a, float b) {
  float2 t; t.x = a; t.y = b;
  __hip_bfloat162 h = __float22bfloat162_rn(t);
  union { __hip_bfloat162 h; unsigned u; } c; c.h = h;
  return c.u;
}
DEV_INLINE unsigned f2h2(float a, float b) {
  __half2 h = __floats2half2_rn(a, b);
  union { __half2 h; unsigned u; } c; c.h = h;
  return c.u;
}
DEV_INLINE float2 h2f2(unsigned u) {
  union { unsigned u; __half2 h; } c; c.u = u;
  return __half22float2(c.h);
}

// Fully fused deform layer over NHWC bf16: per block (64 positions = one
// 64-px row segment, 4 waves x 16 pos, full K):
//   Phase 1: offset/mask conv (NT=2, wOM streamed from global, no LDS,
//            1-iteration source prefetch) -> bias + 2*sigmoid -> sOff LDS.
//   Phase 2: per-lane bilinear table in REGISTERS (9 taps: packed row-pair id
//            + 4 fp16 weights = 27 VGPRs; K-loop fully unrolled).
//   Phase 3: deform GEMM, ZERO barriers / ZERO LDS: A fragments streamed
//            directly from L2-hot wS (same 8 KB chunk read by all 16 waves of
//            a CU -> mostly L1 hits); data-dependent bilinear gathers
//            software-prefetched 1 chunk ahead so scatter latency hides under
//            the blend VALU work. Waves run free (latency-bound fix).
// Chunk ch<36: tap=ch>>2, cg=ch&3, k=q*8+j -> channel cg*32+q*8+j at tap.
// LAYER 1 (BN): +chunk 36 (A rows = BN1-shift cols; B = wt-sum / validity);
//   epilogue PReLU -> NHWC bf16. LAYER 2: 36 chunks; BN2 + NCHW residual.
template<int LAYER>
__global__ __launch_bounds__(256, 4)
void fusedL(const unsigned short* __restrict__ src,     // NHWC bf16
            const unsigned short* __restrict__ wOM,     // [37][2][64][8]
            const unsigned short* __restrict__ wS,      // [37][8][64][8]
            const float* __restrict__ bias,             // [32]
            const float* __restrict__ pA, const float* __restrict__ pB,
            const float* __restrict__ pM, const float* __restrict__ pV,
            const float* __restrict__ resid,
            unsigned short* __restrict__ outh,          // LAYER1 NHWC bf16
            float* __restrict__ outf)                   // LAYER2 NCHW fp32
{
  constexpr bool BN = (LAYER == 1);
  __shared__ __attribute__((aligned(16))) float sOff[64 * 29];   // 7424 B

  const int tid  = threadIdx.x;
  const int lane = tid & 63;
  const int m16  = lane & 15;
  const int q    = lane >> 4;
  const int wv   = tid >> 6;

  const int raw  = blockIdx.x;                // 1024 blocks
  const int xcd  = raw & 7;
  const int slot = raw >> 3;                  // [0,128)
  const int b    = xcd >> 1;
  const int hy   = ((xcd & 1) << 6) | (slot >> 1);
  const int hx0  = (slot & 1) << 6;           // 64-wide segment
  const unsigned short* __restrict__ srcB = src + ((size_t)b << 14) * C;

  const int pos = (wv << 4) + m16;            // block-local position
  const int hx  = hx0 + pos;
  const int cbq = q << 3;

  // ================= Phase 1: offset/mask conv (no LDS, prefetched) ========
  f32x4 acc2[2];
  acc2[0] = (f32x4){0.f, 0.f, 0.f, 0.f};
  acc2[1] = (f32x4){0.f, 0.f, 0.f, 0.f};

  ushort8v pv;
  bool pvok;
  {
    const int iy = hy - 1, ix = hx - 1;       // ch=0: tap 0 (ky=0,kx=0), cg=0
    pvok = ((unsigned)iy < (unsigned)H) && ((unsigned)ix < (unsigned)W);
    const int rb = pvok ? (iy * W + ix) : 0;
    pv = *(const ushort8v*)(srcB + ((size_t)rb * C + cbq));
  }

  #pragma unroll
  for (int ch = 0; ch < 36; ++ch) {
    const unsigned short* ap = wOM + ((size_t)(ch * 128 + lane)) * 8;
    const short8 a0 = *(const short8*)(ap);
    const short8 a1 = *(const short8*)(ap + 512);
    ushort8v nv = pv;
    bool nok = false;
    if (ch + 1 < 36) {
      const int tap = (ch + 1) >> 2, cg = (ch + 1) & 3;
      const int ky = tap / 3, kx = tap - 3 * (tap / 3);
      const int iy = hy + ky - 1;
      const int ix = hx + kx - 1;
      nok = ((unsigned)iy < (unsigned)H) && ((unsigned)ix < (unsigned)W);
      const int rb = nok ? (iy * W + ix) : 0;
      nv = *(const ushort8v*)(srcB + ((size_t)rb * C + (cg << 5) + cbq));
    }
    union { ushort8v v; unsigned u[4]; short8 s; } bfr;
    bfr.v = pv;
    if (!pvok) { bfr.u[0] = 0; bfr.u[1] = 0; bfr.u[2] = 0; bfr.u[3] = 0; }
    acc2[0] = __builtin_amdgcn_mfma_f32_16x16x32_bf16(a0, bfr.s, acc2[0], 0, 0, 0);
    acc2[1] = __builtin_amdgcn_mfma_f32_16x16x32_bf16(a1, bfr.s, acc2[1], 0, 0, 0);
    pv = nv; pvok = nok;
  }
  if constexpr (BN) {   // validity column chunk
    union { unsigned u[4]; short8 s; } bfr;
    float sv[8];
    #pragma unroll
    for (int j = 0; j < 8; ++j) {
      const int kj = cbq + j;
      float s = 0.f;
      if (kj < KK) {
        const int ky = kj / 3, kx = kj - 3 * (kj / 3);
        const int iy = hy + ky - 1, ix = hx + kx - 1;
        s = (((unsigned)iy < (unsigned)H) && ((unsigned)ix < (unsigned)W)) ? 1.f : 0.f;
      }
      sv[j] = s;
    }
    #pragma unroll
    for (int t = 0; t < 4; ++t) bfr.u[t] = pack2bf(sv[2 * t], sv[2 * t + 1]);
    const unsigned short* ap = wOM + ((size_t)36 * 128 + lane) * 8;
    acc2[0] = __builtin_amdgcn_mfma_f32_16x16x32_bf16(*(const short8*)(ap), bfr.s, acc2[0], 0, 0, 0);
    acc2[1] = __builtin_amdgcn_mfma_f32_16x16x32_bf16(*(const short8*)(ap + 512), bfr.s, acc2[1], 0, 0, 0);
  }
  // epilogue -> sOff (D col = m16 -> pos, row = q*4+rg -> o)
  #pragma unroll
  for (int ot = 0; ot < 2; ++ot) {
    #pragma unroll
    for (int rg = 0; rg < 4; ++rg) {
      const int o = ot * 16 + (q << 2) + rg;
      if (o < 27) {
        float v = acc2[ot][rg] + bias[o];
        if (o >= 18) v = 2.f / (1.f + expf(-v));
        sOff[pos * 29 + o] = v;
      }
    }
  }
  __syncthreads();

  // ================= Phase 2: per-lane bilinear table (registers) ==========
  unsigned tId[9], tW01[9], tW23[9];
  {
    const float* myOff = sOff + pos * 29;
    #pragma unroll
    for (int tap = 0; tap < 9; ++tap) {
      const int ky = tap / 3, kx = tap - 3 * (tap / 3);
      const float oy = myOff[2 * tap];
      const float ox = myOff[2 * tap + 1];
      const float mv = myOff[18 + tap];
      const float py = (float)(hy - 1 + ky) + oy;
      const float px = (float)(hx - 1 + kx) + ox;
      const float fy = floorf(py), fx = floorf(px);
      const float ay = py - fy, ax = px - fx;
      const int y0 = (int)fy, x0 = (int)fx;
      const int y1 = y0 + 1, x1 = x0 + 1;
      const float wyt = (1.f - ay) * (((unsigned)y0 < (unsigned)H) ? 1.f : 0.f);
      const float wyb = ay * (((unsigned)y1 < (unsigned)H) ? 1.f : 0.f);
      const int y0c = min(max(y0, 0), H - 1), y1c = min(max(y1, 0), H - 1);
      const int bx  = min(max(x0, 0), W - 2);
      float wA = 0.f, wB = 0.f;
      if (x0 == bx)          { wA = 1.f - ax; wB = ax; }
      else if (x1 == bx)     { wA = ax; }
      else if (x0 == bx + 1) { wB = 1.f - ax; }
      tId[tap]  = (unsigned)(y0c * W + bx) | ((unsigned)(y1c * W + bx) << 16);
      tW01[tap] = f2h2(mv * wyt * wA, mv * wyt * wB);
      tW23[tap] = f2h2(mv * wyb * wA, mv * wyb * wB);
    }
  }

  // ================= Phase 3: deform GEMM (no LDS, no barriers) ============
  f32x4 acc[8];
  #pragma unroll
  for (int i = 0; i < 8; ++i) acc[i] = (f32x4){0.f, 0.f, 0.f, 0.f};

  // gather prefetch for chunk 0
  ushort8v TL, TR, BL, BR;
  {
    const unsigned idp = tId[0];
    const unsigned short* pT  = srcB + ((size_t)(idp & 0xFFFFu) * C + cbq);
    const unsigned short* pBt = srcB + ((size_t)(idp >> 16) * C + cbq);
    TL = *(const ushort8v*)(pT);
    TR = *(const ushort8v*)(pT + C);
    BL = *(const ushort8v*)(pBt);
    BR = *(const ushort8v*)(pBt + C);
  }

  #pragma unroll
  for (int tap = 0; tap < 9; ++tap) {
    #pragma unroll
    for (int cg = 0; cg < 4; ++cg) {
      const int ch = (tap << 2) + cg;
      // A fragments direct from global (L2/L1-hot, shared by all blocks)
      const unsigned short* ap = wS + ((size_t)(ch * 512 + lane)) * 8;
      short8 af[8];
      #pragma unroll
      for (int ot = 0; ot < 8; ++ot)
        af[ot] = *(const short8*)(ap + ot * 512);
      // prefetch next chunk's gathers (latency hides under the blend below)
      ushort8v nTL = TL, nTR = TR, nBL = BL, nBR = BR;
      if (ch + 1 < 36) {
        const unsigned idp = tId[(ch + 1) >> 2];
        const int cbase = (((ch + 1) & 3) << 5) + cbq;
        const unsigned short* pT  = srcB + ((size_t)(idp & 0xFFFFu) * C + cbase);
        const unsigned short* pBt = srcB + ((size_t)(idp >> 16) * C + cbase);
        nTL = *(const ushort8v*)(pT);
        nTR = *(const ushort8v*)(pT + C);
        nBL = *(const ushort8v*)(pBt);
        nBR = *(const ushort8v*)(pBt + C);
      }
      // blend current gathers -> B fragment
      const float2 w01 = h2f2(tW01[tap]);
      const float2 w23 = h2f2(tW23[tap]);
      union { unsigned u[4]; short8 s; } bfr;
      #pragma unroll
      for (int t = 0; t < 4; ++t) {
        const float sv0 = w01.x * bfu(TL[2 * t])     + w01.y * bfu(TR[2 * t])
                        + w23.x * bfu(BL[2 * t])     + w23.y * bfu(BR[2 * t]);
        const float sv1 = w01.x * bfu(TL[2 * t + 1]) + w01.y * bfu(TR[2 * t + 1])
                        + w23.x * bfu(BL[2 * t + 1]) + w23.y * bfu(BR[2 * t + 1]);
        bfr.u[t] = pack2bf(sv0, sv1);
      }
      #pragma unroll
      for (int ot = 0; ot < 8; ++ot)
        acc[ot] = __builtin_amdgcn_mfma_f32_16x16x32_bf16(af[ot], bfr.s, acc[ot], 0, 0, 0);
      TL = nTL; TR = nTR; BL = nBL; BR = nBR;
    }
  }

  if constexpr (BN) {   // chunk 36: BN-shift column (B = wt sums, from regs)
    float sv[8];
    if (q == 0) {
      #pragma unroll
      for (int j = 0; j < 8; ++j) {
        const float2 a = h2f2(tW01[j]);
        const float2 c = h2f2(tW23[j]);
        sv[j] = a.x + a.y + c.x + c.y;
      }
    } else if (q == 1) {
      const float2 a = h2f2(tW01[8]);
      const float2 c = h2f2(tW23[8]);
      sv[0] = a.x + a.y + c.x + c.y;
      #pragma unroll
      for (int j = 1; j < 8; ++j) sv[j] = 0.f;
    } else {
      #pragma unroll
      for (int j = 0; j < 8; ++j) sv[j] = 0.f;
    }
    union { unsigned u[4]; short8 s; } bfr;
    #pragma unroll
    for (int t = 0; t < 4; ++t) bfr.u[t] = pack2bf(sv[2 * t], sv[2 * t + 1]);
    const unsigned short* ap = wS + ((size_t)(36 * 512 + lane)) * 8;
    #pragma unroll
    for (int ot = 0; ot < 8; ++ot) {
      const short8 afr = *(const short8*)(ap + ot * 512);
      acc[ot] = __builtin_amdgcn_mfma_f32_16x16x32_bf16(afr, bfr.s, acc[ot], 0, 0, 0);
    }
  }

  // ---- epilogue ----
  #pragma unroll
  for (int ot = 0; ot < 8; ++ot) {
    if constexpr (LAYER == 1) {
      const float a0 = pA[ot * 16 + (q << 2) + 0];
      const float a1 = pA[ot * 16 + (q << 2) + 1];
      const float a2 = pA[ot * 16 + (q << 2) + 2];
      const float a3 = pA[ot * 16 + (q << 2) + 3];
      const float v0 = acc[ot][0], v1 = acc[ot][1];
      const float v2 = acc[ot][2], v3 = acc[ot][3];
      uint2 st;
      st.x = pack2bf(v0 > 0.f ? v0 : a0 * v0, v1 > 0.f ? v1 : a1 * v1);
      st.y = pack2bf(v2 > 0.f ? v2 : a2 * v2, v3 > 0.f ? v3 : a3 * v3);
      const int n = (b << 14) + hy * W + hx;
      *(uint2*)(outh + (size_t)n * C + ot * 16 + (q << 2)) = st;
    } else {
      #pragma unroll
      for (int rg = 0; rg < 4; ++rg) {
        const int o = ot * 16 + (q << 2) + rg;
        const float vv = acc[ot][rg];
        const size_t oi = (((size_t)(b * C + o)) << 14) + hy * W + hx;
        const float s  = pA[o] * rsqrtf(pV[o] + 1e-5f);
        const float sh = pB[o] - pM[o] * s;
        outf[oi] = vv * s + sh + resid[oi];
      }
    }
  }
}

// NCHW fp32 -> NHWC bf16, LDS-tiled (coalesced loads AND stores)
__global__ __launch_bounds__(256, 4)
void xcvt3(const float* __restrict__ x, unsigned short* __restrict__ xb)
{
  __shared__ unsigned tile[64 * 69];
  const int b   = blockIdx.y;
  const int p0  = blockIdx.x * 64;
  const int tid = threadIdx.x;
  const int pl  = tid & 63;
  const int cg  = tid >> 6;
  const float* __restrict__ xp = x + (((size_t)(b * C) + cg * 32) << 14) + p0 + pl;
  #pragma unroll
  for (int j = 0; j < 16; ++j) {
    const float a = xp[(size_t)(2 * j) << 14];
    const float c = xp[(size_t)(2 * j + 1) << 14];
    tile[pl * 69 + cg * 16 + j] = pack2bf(a, c);
  }
  __syncthreads();
  const int pl2 = tid >> 2;
  const int cq  = tid & 3;
  unsigned* dst = (unsigned*)(xb + (((size_t)(b << 14)) + p0 + pl2) * C + cq * 32);
  #pragma unroll
  for (int k = 0; k < 16; k += 4) {
    uint4 v;
    v.x = tile[pl2 * 69 + cq * 16 + k];
    v.y = tile[pl2 * 69 + cq * 16 + k + 1];
    v.z = tile[pl2 * 69 + cq * 16 + k + 2];
    v.w = tile[pl2 * 69 + cq * 16 + k + 3];
    *(uint4*)(dst + k) = v;
  }
}

// Swizzled weights, tap-major chunks: wS[((ch*NT+ot)*64+lane)*8+j] =
// w[o=ot*16+(lane&15)][c=(ch&3)*32+(lane>>4)*8+j][tap=ch>>2] (ch<36);
// ch==36: BN-shift col (kj=(lane>>4)*8+j < 9), layer-1 only.
__global__ void prep5(const float* __restrict__ w1, const float* __restrict__ w2,
                      const float* __restrict__ ow1, const float* __restrict__ mw1,
                      const float* __restrict__ ob1, const float* __restrict__ mb1,
                      const float* __restrict__ ow2, const float* __restrict__ mw2,
                      const float* __restrict__ ob2, const float* __restrict__ mb2,
                      const float* __restrict__ g, const float* __restrict__ bb,
                      const float* __restrict__ m, const float* __restrict__ v,
                      unsigned short* __restrict__ wb1, unsigned short* __restrict__ wb2,
                      unsigned short* __restrict__ wom1, unsigned short* __restrict__ wom2,
                      float* __restrict__ bias1, float* __restrict__ bias2)
{
  const int i = blockIdx.x * 256 + threadIdx.x;
  if (i < 128 * KT2) {              // deform, NT=8
    const int j = i & 7, lane = (i >> 3) & 63, ot = (i >> 9) & 7, ch = i >> 12;
    const int o = ot * 16 + (lane & 15);
    const int qj = ((lane >> 4) << 3) + j;
    unsigned short v1 = 0, v2 = 0;
    if (ch < 36) {
      const int tap = ch >> 2;
      const int c   = ((ch & 3) << 5) + qj;
      const float s = g[c] * rsqrtf(v[c] + 1e-5f);
      v1 = f2bf(w1[(size_t)(o * 128 + c) * 9 + tap] * s);
      v2 = f2bf(w2[(size_t)(o * 128 + c) * 9 + tap]);
    } else if (qj < KK) {
      float acc = 0.f;
      for (int c = 0; c < 128; ++c) {
        const float s  = g[c] * rsqrtf(v[c] + 1e-5f);
        const float sh = bb[c] - m[c] * s;
        acc += w1[(size_t)(o * 128 + c) * 9 + qj] * sh;
      }
      v1 = f2bf(acc);
    }
    wb1[i] = v1; wb2[i] = v2;
  }
  if (i < 32 * KT2) {               // offset/mask, NT=2
    const int j = i & 7, lane = (i >> 3) & 63, ot = (i >> 9) & 1, ch = i >> 10;
    const int o = ot * 16 + (lane & 15);
    const int qj = ((lane >> 4) << 3) + j;
    unsigned short v1 = 0, v2 = 0;
    if (ch < 36) {
      const int tap = ch >> 2;
      const int c   = ((ch & 3) << 5) + qj;
      const float s = g[c] * rsqrtf(v[c] + 1e-5f);
      if (o < 18) {
        v1 = f2bf(ow1[(size_t)(o * 128 + c) * 9 + tap] * s);
        v2 = f2bf(ow2[(size_t)(o * 128 + c) * 9 + tap]);
      } else if (o < 27) {
        v1 = f2bf(mw1[(size_t)((o - 18) * 128 + c) * 9 + tap] * s);
        v2 = f2bf(mw2[(size_t)((o - 18) * 128 + c) * 9 + tap]);
      }
    } else if (qj < KK && o < 27) {
      const float* wsrc = (o < 18) ? ow1 + (size_t)o * 1152
                                   : mw1 + (size_t)(o - 18) * 1152;
      float acc = 0.f;
      for (int c = 0; c < 128; ++c) {
        const float s  = g[c] * rsqrtf(v[c] + 1e-5f);
        const float sh = bb[c] - m[c] * s;
        acc += wsrc[(size_t)c * 9 + qj] * sh;
      }
      v1 = f2bf(acc);
    }
    wom1[i] = v1; wom2[i] = v2;
  }
  if (i < 32) {
    float b1 = 0.f, b2 = 0.f;
    if (i < 18)      { b1 = ob1[i];      b2 = ob2[i]; }
    else if (i < 27) { b1 = mb1[i - 18]; b2 = mb2[i - 18]; }
    bias1[i] = b1; bias2[i] = b2;
  }
}

extern "C" void kernel_launch(void* const* d_in, const int* in_sizes, int n_in,
                              void* d_out, int out_size, void* d_ws, size_t ws_size,
                              hipStream_t stream)
{
  const float* x     = (const float*)d_in[0];
  const float* bn1g  = (const float*)d_in[1];
  const float* bn1b  = (const float*)d_in[2];
  const float* bn1m  = (const float*)d_in[3];
  const float* bn1v  = (const float*)d_in[4];
  const float* ow1   = (const float*)d_in[5];
  const float* ob1   = (const float*)d_in[6];
  const float* mw1   = (const float*)d_in[7];
  const float* mb1   = (const float*)d_in[8];
  const float* w1    = (const float*)d_in[9];
  const float* alpha = (const float*)d_in[10];
  const float* ow2   = (const float*)d_in[11];
  const float* ob2   = (const float*)d_in[12];
  const float* mw2   = (const float*)d_in[13];
  const float* mb2   = (const float*)d_in[14];
  const float* w2    = (const float*)d_in[15];
  const float* bn2g  = (const float*)d_in[16];
  const float* bn2b  = (const float*)d_in[17];
  const float* bn2m  = (const float*)d_in[18];
  const float* bn2v  = (const float*)d_in[19];
  float* out = (float*)d_out;

  char* wsp = (char*)d_ws;
  unsigned short* xbf  = (unsigned short*)(wsp);             // NHWC bf16
  unsigned short* r2bf = (unsigned short*)(wsp + 16777216);  // NHWC bf16
  unsigned short* wb1  = (unsigned short*)(wsp + 40632320);  // 303104
  unsigned short* wb2  = (unsigned short*)(wsp + 40935424);  // 303104
  unsigned short* wom1 = (unsigned short*)(wsp + 41238528);  // 75776
  unsigned short* wom2 = (unsigned short*)(wsp + 41314304);  // 75776
  float* bias1 = (float*)(wsp + 41390080);
  float* bias2 = (float*)(wsp + 41390208);

  xcvt3<<<dim3(256, 4), 256, 0, stream>>>(x, xbf);
  prep5<<<(128 * KT2 + 255) / 256, 256, 0, stream>>>(
      w1, w2, ow1, mw1, ob1, mb1, ow2, mw2, ob2, mb2,
      bn1g, bn1b, bn1m, bn1v, wb1, wb2, wom1, wom2, bias1, bias2);

  fusedL<1><<<1024, 256, 0, stream>>>(xbf, wom1, wb1, bias1, alpha,
      nullptr, nullptr, nullptr, nullptr, r2bf, nullptr);
  fusedL<2><<<1024, 256, 0, stream>>>(r2bf, wom2, wb2, bias2, bn2g,
      bn2b, bn2m, bn2v, x, nullptr, out);
}

// Round 2
// 344.281 us; speedup vs baseline: 1.1093x; 1.1093x over previous
//
#include <hip/hip_runtime.h>
#include <hip/hip_bf16.h>
#include <hip/hip_fp16.h>
#include <math.h>

#define DEV_INLINE __device__ __forceinline__

typedef __attribute__((ext_vector_type(8))) short short8;
typedef __attribute__((ext_vector_type(8))) unsigned short ushort8v;
typedef __attribute__((ext_vector_type(4))) float f32x4;

constexpr int H = 128, W = 128, C = 128, B = 4;
constexpr int KK = 9;
constexpr int KT2 = 1184;         // 37 chunks * 32

DEV_INLINE unsigned short f2bf(float f) {
  union { float f; unsigned u; } v; v.f = f;
  unsigned r = v.u + 0x7FFFu + ((v.u >> 16) & 1u);   // RNE
  return (unsigned short)(r >> 16);
}
DEV_INLINE float ubits(unsigned u) {
  union { unsigned u; float f; } v; v.u = u; return v.f;
}
DEV_INLINE float bfu(unsigned short u) { return ubits(((unsigned)u) << 16); }
DEV_INLINE unsigned pack2bf(float a, float b) {
  float2 t; t.x = a; t.y = b;
  __hip_bfloat162 h = __float22bfloat162_rn(t);
  union { __hip_bfloat162 h; unsigned u; } c; c.h = h;
  return c.u;
}
DEV_INLINE unsigned f2h2(float a, float b) {
  __half2 h = __floats2half2_rn(a, b);
  union { __half2 h; unsigned u; } c; c.h = h;
  return c.u;
}
DEV_INLINE float2 h2f2(unsigned u) {
  union { unsigned u; __half2 h; } c; c.u = u;
  return __half22float2(c.h);
}
// async global->LDS, 16B per lane (wave-uniform LDS base + lane*16)
DEV_INLINE void gload_lds16(const unsigned short* g, unsigned short* l) {
  __builtin_amdgcn_global_load_lds(
      (const __attribute__((address_space(1))) unsigned*)g,
      (__attribute__((address_space(3))) unsigned*)l, 16, 0, 0);
}

// Fully fused deform layer over NHWC bf16: per block (64 positions = one
// 64-px row segment, 4 waves x 16 pos, full K):
//   Phase 1: offset/mask conv (NT=2, wOM streamed from global, no LDS,
//            1-iteration source prefetch) -> bias + 2*sigmoid -> sOff LDS.
//   Phase 2: per-lane bilinear table in REGISTERS (9 taps: packed row-pair id
//            + 4 fp16 weights = 27 VGPRs; K-loop fully unrolled).
//   Phase 3: deform GEMM, A-tile double-buffered in LDS via global_load_lds
//            (width 16, no VGPR round-trip). Counted-vmcnt pipeline (T3/T4):
//            per chunk {stage ch+1 || fence || blend+8 ds_read+8 MFMA ||
//            gathers ch+2 || s_waitcnt vmcnt(4) + raw s_barrier}. The wait
//            retires staging (issued before the gathers) but keeps the 4
//            newest scattered bilinear loads IN FLIGHT across the barrier --
//            never a vmcnt(0) drain in the main loop (that drain was round
//            0's stall). Gathers are depth-2 prefetched (consumed 2 chunks
//            after issue).
// Chunk ch<36: tap=ch>>2, cg=ch&3, k=q*8+j -> channel cg*32+q*8+j at tap.
// LAYER 1 (BN): +chunk 36 (A rows = BN1-shift cols; B = wt-sum / validity);
//   epilogue PReLU -> NHWC bf16. LAYER 2: 36 chunks; BN2 + NCHW residual.
template<int LAYER>
__global__ __launch_bounds__(256, 4)
void fusedL(const unsigned short* __restrict__ src,     // NHWC bf16
            const unsigned short* __restrict__ wOM,     // [37][2][64][8]
            const unsigned short* __restrict__ wS,      // [37][8][64][8]
            const float* __restrict__ bias,             // [32]
            const float* __restrict__ pA, const float* __restrict__ pB,
            const float* __restrict__ pM, const float* __restrict__ pV,
            const float* __restrict__ resid,
            unsigned short* __restrict__ outh,          // LAYER1 NHWC bf16
            float* __restrict__ outf)                   // LAYER2 NCHW fp32
{
  constexpr bool BN   = (LAYER == 1);
  constexpr int  NCH3 = BN ? 37 : 36;
  __shared__ __attribute__((aligned(16))) char smem[16384];
  float* sOff = (float*)smem;                            // [64][29] = 7424 B
  unsigned short* aBuf0 = (unsigned short*)smem;         // 8 KB (overlays sOff)
  unsigned short* aBuf1 = (unsigned short*)(smem + 8192);

  const int tid  = threadIdx.x;
  const int lane = tid & 63;
  const int m16  = lane & 15;
  const int q    = lane >> 4;
  const int wv   = tid >> 6;

  const int raw  = blockIdx.x;                // 1024 blocks
  const int xcd  = raw & 7;
  const int slot = raw >> 3;                  // [0,128)
  const int b    = xcd >> 1;
  const int hy   = ((xcd & 1) << 6) | (slot >> 1);
  const int hx0  = (slot & 1) << 6;           // 64-wide segment
  const unsigned short* __restrict__ srcB = src + ((size_t)b << 14) * C;

  const int pos = (wv << 4) + m16;            // block-local position
  const int hx  = hx0 + pos;
  const int cbq = q << 3;

  // ================= Phase 1: offset/mask conv (no LDS, prefetched) ========
  f32x4 acc2[2];
  acc2[0] = (f32x4){0.f, 0.f, 0.f, 0.f};
  acc2[1] = (f32x4){0.f, 0.f, 0.f, 0.f};

  ushort8v pv;
  bool pvok;
  {
    const int iy = hy - 1, ix = hx - 1;       // ch=0: tap 0 (ky=0,kx=0), cg=0
    pvok = ((unsigned)iy < (unsigned)H) && ((unsigned)ix < (unsigned)W);
    const int rb = pvok ? (iy * W + ix) : 0;
    pv = *(const ushort8v*)(srcB + ((size_t)rb * C + cbq));
  }

  #pragma unroll
  for (int ch = 0; ch < 36; ++ch) {
    const unsigned short* ap = wOM + ((size_t)(ch * 128 + lane)) * 8;
    const short8 a0 = *(const short8*)(ap);
    const short8 a1 = *(const short8*)(ap + 512);
    ushort8v nv = pv;
    bool nok = false;
    if (ch + 1 < 36) {
      const int tap = (ch + 1) >> 2, cg = (ch + 1) & 3;
      const int ky = tap / 3, kx = tap - 3 * (tap / 3);
      const int iy = hy + ky - 1;
      const int ix = hx + kx - 1;
      nok = ((unsigned)iy < (unsigned)H) && ((unsigned)ix < (unsigned)W);
      const int rb = nok ? (iy * W + ix) : 0;
      nv = *(const ushort8v*)(srcB + ((size_t)rb * C + (cg << 5) + cbq));
    }
    union { ushort8v v; unsigned u[4]; short8 s; } bfr;
    bfr.v = pv;
    if (!pvok) { bfr.u[0] = 0; bfr.u[1] = 0; bfr.u[2] = 0; bfr.u[3] = 0; }
    acc2[0] = __builtin_amdgcn_mfma_f32_16x16x32_bf16(a0, bfr.s, acc2[0], 0, 0, 0);
    acc2[1] = __builtin_amdgcn_mfma_f32_16x16x32_bf16(a1, bfr.s, acc2[1], 0, 0, 0);
    pv = nv; pvok = nok;
  }
  if constexpr (BN) {   // validity column chunk
    union { unsigned u[4]; short8 s; } bfr;
    float sv[8];
    #pragma unroll
    for (int j = 0; j < 8; ++j) {
      const int kj = cbq + j;
      float s = 0.f;
      if (kj < KK) {
        const int ky = kj / 3, kx = kj - 3 * (kj / 3);
        const int iy = hy + ky - 1, ix = hx + kx - 1;
        s = (((unsigned)iy < (unsigned)H) && ((unsigned)ix < (unsigned)W)) ? 1.f : 0.f;
      }
      sv[j] = s;
    }
    #pragma unroll
    for (int t = 0; t < 4; ++t) bfr.u[t] = pack2bf(sv[2 * t], sv[2 * t + 1]);
    const unsigned short* ap = wOM + ((size_t)36 * 128 + lane) * 8;
    acc2[0] = __builtin_amdgcn_mfma_f32_16x16x32_bf16(*(const short8*)(ap), bfr.s, acc2[0], 0, 0, 0);
    acc2[1] = __builtin_amdgcn_mfma_f32_16x16x32_bf16(*(const short8*)(ap + 512), bfr.s, acc2[1], 0, 0, 0);
  }
  // epilogue -> sOff (D col = m16 -> pos, row = q*4+rg -> o)
  #pragma unroll
  for (int ot = 0; ot < 2; ++ot) {
    #pragma unroll
    for (int rg = 0; rg < 4; ++rg) {
      const int o = ot * 16 + (q << 2) + rg;
      if (o < 27) {
        float v = acc2[ot][rg] + bias[o];
        if (o >= 18) v = 2.f / (1.f + expf(-v));
        sOff[pos * 29 + o] = v;
      }
    }
  }
  __syncthreads();

  // ================= Phase 2: per-lane bilinear table (registers) ==========
  unsigned tId[9], tW01[9], tW23[9];
  {
    const float* myOff = sOff + pos * 29;
    #pragma unroll
    for (int tap = 0; tap < 9; ++tap) {
      const int ky = tap / 3, kx = tap - 3 * (tap / 3);
      const float oy = myOff[2 * tap];
      const float ox = myOff[2 * tap + 1];
      const float mv = myOff[18 + tap];
      const float py = (float)(hy - 1 + ky) + oy;
      const float px = (float)(hx - 1 + kx) + ox;
      const float fy = floorf(py), fx = floorf(px);
      const float ay = py - fy, ax = px - fx;
      const int y0 = (int)fy, x0 = (int)fx;
      const int y1 = y0 + 1, x1 = x0 + 1;
      const float wyt = (1.f - ay) * (((unsigned)y0 < (unsigned)H) ? 1.f : 0.f);
      const float wyb = ay * (((unsigned)y1 < (unsigned)H) ? 1.f : 0.f);
      const int y0c = min(max(y0, 0), H - 1), y1c = min(max(y1, 0), H - 1);
      const int bx  = min(max(x0, 0), W - 2);
      float wA = 0.f, wB = 0.f;
      if (x0 == bx)          { wA = 1.f - ax; wB = ax; }
      else if (x1 == bx)     { wA = ax; }
      else if (x0 == bx + 1) { wB = 1.f - ax; }
      tId[tap]  = (unsigned)(y0c * W + bx) | ((unsigned)(y1c * W + bx) << 16);
      tW01[tap] = f2h2(mv * wyt * wA, mv * wyt * wB);
      tW23[tap] = f2h2(mv * wyb * wA, mv * wyb * wB);
    }
  }
  __syncthreads();   // sOff dead; aBuf0 may now be written

  // ================= Phase 3: deform GEMM (counted-vmcnt pipeline) =========
  f32x4 acc[8];
  #pragma unroll
  for (int i = 0; i < 8; ++i) acc[i] = (f32x4){0.f, 0.f, 0.f, 0.f};

  ushort8v gTL[2], gTR[2], gBL[2], gBR[2];   // depth-2 gather pipeline

  // prologue: stage chunk 0 weights, then gathers for chunks 0 and 1
  {
    unsigned short* dst0 = aBuf0 + (wv << 9);        // wave-uniform base
    gload_lds16(wS + (size_t)tid * 8, dst0);
    gload_lds16(wS + (size_t)(256 + tid) * 8, dst0 + 2048);
  }
  asm volatile("" ::: "memory");   // staging issued before gathers (vmcnt order)
  #pragma unroll
  for (int pc = 0; pc < 2; ++pc) {
    const unsigned idp = tId[0];                     // chunks 0,1 are tap 0
    const int cbase = (pc << 5) + cbq;
    const unsigned short* pT  = srcB + ((size_t)(idp & 0xFFFFu) * C + cbase);
    const unsigned short* pBt = srcB + ((size_t)(idp >> 16) * C + cbase);
    gTL[pc] = *(const ushort8v*)(pT);
    gTR[pc] = *(const ushort8v*)(pT + C);
    gBL[pc] = *(const ushort8v*)(pBt);
    gBR[pc] = *(const ushort8v*)(pBt + C);
  }
  asm volatile("s_waitcnt vmcnt(8)" ::: "memory");   // staging(0) retired
  __builtin_amdgcn_s_barrier();
  __builtin_amdgcn_sched_barrier(0);

  #pragma unroll
  for (int ch = 0; ch < 36; ++ch) {
    // ---- C: stage next chunk's weights (async, to the other buffer) ----
    if (ch + 1 < NCH3) {
      unsigned short* wd = ((ch + 1) & 1) ? aBuf1 : aBuf0;
      unsigned short* dst = wd + (wv << 9);
      const size_t gb = (size_t)(ch + 1) * 4096;
      gload_lds16(wS + gb + (size_t)tid * 8, dst);
      gload_lds16(wS + gb + (size_t)(256 + tid) * 8, dst + 2048);
    }
    asm volatile("" ::: "memory");   // pin staging before this iter's gathers

    // ---- A: blend current gathers -> B fragment ----
    const int tap = ch >> 2;
    const float2 w01 = h2f2(tW01[tap]);
    const float2 w23 = h2f2(tW23[tap]);
    const ushort8v TL = gTL[ch & 1], TR = gTR[ch & 1];
    const ushort8v BL = gBL[ch & 1], BR = gBR[ch & 1];
    union { unsigned u[4]; short8 s; } bfr;
    #pragma unroll
    for (int t = 0; t < 4; ++t) {
      const float sv0 = w01.x * bfu(TL[2 * t])     + w01.y * bfu(TR[2 * t])
                      + w23.x * bfu(BL[2 * t])     + w23.y * bfu(BR[2 * t]);
      const float sv1 = w01.x * bfu(TL[2 * t + 1]) + w01.y * bfu(TR[2 * t + 1])
                      + w23.x * bfu(BL[2 * t + 1]) + w23.y * bfu(BR[2 * t + 1]);
      bfr.u[t] = pack2bf(sv0, sv1);
    }

    // ---- B: A-fragments from LDS + MFMA ----
    const unsigned short* rbuf = (ch & 1) ? aBuf1 : aBuf0;
    #pragma unroll
    for (int ot = 0; ot < 8; ++ot) {
      const short8 afr = *(const short8*)(rbuf + ((size_t)(ot * 64 + lane)) * 8);
      acc[ot] = __builtin_amdgcn_mfma_f32_16x16x32_bf16(afr, bfr.s, acc[ot], 0, 0, 0);
    }

    // ---- D: issue gathers for chunk ch+2 (consumed 2 iters later) ----
    if (ch + 2 < 36) {
      const int nch = ch + 2;
      const unsigned idp = tId[nch >> 2];
      const int cbase = ((nch & 3) << 5) + cbq;
      const unsigned short* pT  = srcB + ((size_t)(idp & 0xFFFFu) * C + cbase);
      const unsigned short* pBt = srcB + ((size_t)(idp >> 16) * C + cbase);
      gTL[ch & 1] = *(const ushort8v*)(pT);
      gTR[ch & 1] = *(const ushort8v*)(pT + C);
      gBL[ch & 1] = *(const ushort8v*)(pBt);
      gBR[ch & 1] = *(const ushort8v*)(pBt + C);
    }

    // ---- E: counted wait (staging retired, newest gathers stay in flight)
    if (ch + 1 < NCH3) {
      if (ch < 34) { asm volatile("s_waitcnt vmcnt(4)" ::: "memory"); }
      else         { asm volatile("s_waitcnt vmcnt(0)" ::: "memory"); }
      __builtin_amdgcn_s_barrier();
      __builtin_amdgcn_sched_barrier(0);
    }
  }

  if constexpr (BN) {   // chunk 36: BN-shift column (B = wt sums, from regs)
    float sv[8];
    if (q == 0) {
      #pragma unroll
      for (int j = 0; j < 8; ++j) {
        const float2 a = h2f2(tW01[j]);
        const float2 c = h2f2(tW23[j]);
        sv[j] = a.x + a.y + c.x + c.y;
      }
    } else if (q == 1) {
      const float2 a = h2f2(tW01[8]);
      const float2 c = h2f2(tW23[8]);
      sv[0] = a.x + a.y + c.x + c.y;
      #pragma unroll
      for (int j = 1; j < 8; ++j) sv[j] = 0.f;
    } else {
      #pragma unroll
      for (int j = 0; j < 8; ++j) sv[j] = 0.f;
    }
    union { unsigned u[4]; short8 s; } bfr;
    #pragma unroll
    for (int t = 0; t < 4; ++t) bfr.u[t] = pack2bf(sv[2 * t], sv[2 * t + 1]);
    #pragma unroll
    for (int ot = 0; ot < 8; ++ot) {
      const short8 afr = *(const short8*)(aBuf0 + ((size_t)(ot * 64 + lane)) * 8);
      acc[ot] = __builtin_amdgcn_mfma_f32_16x16x32_bf16(afr, bfr.s, acc[ot], 0, 0, 0);
    }
  }

  // ---- epilogue ----
  #pragma unroll
  for (int ot = 0; ot < 8; ++ot) {
    if constexpr (LAYER == 1) {
      const float a0 = pA[ot * 16 + (q << 2) + 0];
      const float a1 = pA[ot * 16 + (q << 2) + 1];
      const float a2 = pA[ot * 16 + (q << 2) + 2];
      const float a3 = pA[ot * 16 + (q << 2) + 3];
      const float v0 = acc[ot][0], v1 = acc[ot][1];
      const float v2 = acc[ot][2], v3 = acc[ot][3];
      uint2 st;
      st.x = pack2bf(v0 > 0.f ? v0 : a0 * v0, v1 > 0.f ? v1 : a1 * v1);
      st.y = pack2bf(v2 > 0.f ? v2 : a2 * v2, v3 > 0.f ? v3 : a3 * v3);
      const int n = (b << 14) + hy * W + hx;
      *(uint2*)(outh + (size_t)n * C + ot * 16 + (q << 2)) = st;
    } else {
      #pragma unroll
      for (int rg = 0; rg < 4; ++rg) {
        const int o = ot * 16 + (q << 2) + rg;
        const float vv = acc[ot][rg];
        const size_t oi = (((size_t)(b * C + o)) << 14) + hy * W + hx;
        const float s  = pA[o] * rsqrtf(pV[o] + 1e-5f);
        const float sh = pB[o] - pM[o] * s;
        outf[oi] = vv * s + sh + resid[oi];
      }
    }
  }
}

// NCHW fp32 -> NHWC bf16, LDS-tiled (coalesced loads AND stores)
__global__ __launch_bounds__(256, 4)
void xcvt3(const float* __restrict__ x, unsigned short* __restrict__ xb)
{
  __shared__ unsigned tile[64 * 69];
  const int b   = blockIdx.y;
  const int p0  = blockIdx.x * 64;
  const int tid = threadIdx.x;
  const int pl  = tid & 63;
  const int cg  = tid >> 6;
  const float* __restrict__ xp = x + (((size_t)(b * C) + cg * 32) << 14) + p0 + pl;
  #pragma unroll
  for (int j = 0; j < 16; ++j) {
    const float a = xp[(size_t)(2 * j) << 14];
    const float c = xp[(size_t)(2 * j + 1) << 14];
    tile[pl * 69 + cg * 16 + j] = pack2bf(a, c);
  }
  __syncthreads();
  const int pl2 = tid >> 2;
  const int cq  = tid & 3;
  unsigned* dst = (unsigned*)(xb + (((size_t)(b << 14)) + p0 + pl2) * C + cq * 32);
  #pragma unroll
  for (int k = 0; k < 16; k += 4) {
    uint4 v;
    v.x = tile[pl2 * 69 + cq * 16 + k];
    v.y = tile[pl2 * 69 + cq * 16 + k + 1];
    v.z = tile[pl2 * 69 + cq * 16 + k + 2];
    v.w = tile[pl2 * 69 + cq * 16 + k + 3];
    *(uint4*)(dst + k) = v;
  }
}

// Swizzled weights, tap-major chunks: wS[((ch*NT+ot)*64+lane)*8+j] =
// w[o=ot*16+(lane&15)][c=(ch&3)*32+(lane>>4)*8+j][tap=ch>>2] (ch<36);
// ch==36: BN-shift col (kj=(lane>>4)*8+j < 9), layer-1 only.
__global__ void prep5(const float* __restrict__ w1, const float* __restrict__ w2,
                      const float* __restrict__ ow1, const float* __restrict__ mw1,
                      const float* __restrict__ ob1, const float* __restrict__ mb1,
                      const float* __restrict__ ow2, const float* __restrict__ mw2,
                      const float* __restrict__ ob2, const float* __restrict__ mb2,
                      const float* __restrict__ g, const float* __restrict__ bb,
                      const float* __restrict__ m, const float* __restrict__ v,
                      unsigned short* __restrict__ wb1, unsigned short* __restrict__ wb2,
                      unsigned short* __restrict__ wom1, unsigned short* __restrict__ wom2,
                      float* __restrict__ bias1, float* __restrict__ bias2)
{
  const int i = blockIdx.x * 256 + threadIdx.x;
  if (i < 128 * KT2) {              // deform, NT=8
    const int j = i & 7, lane = (i >> 3) & 63, ot = (i >> 9) & 7, ch = i >> 12;
    const int o = ot * 16 + (lane & 15);
    const int qj = ((lane >> 4) << 3) + j;
    unsigned short v1 = 0, v2 = 0;
    if (ch < 36) {
      const int tap = ch >> 2;
      const int c   = ((ch & 3) << 5) + qj;
      const float s = g[c] * rsqrtf(v[c] + 1e-5f);
      v1 = f2bf(w1[(size_t)(o * 128 + c) * 9 + tap] * s);
      v2 = f2bf(w2[(size_t)(o * 128 + c) * 9 + tap]);
    } else if (qj < KK) {
      float acc = 0.f;
      for (int c = 0; c < 128; ++c) {
        const float s  = g[c] * rsqrtf(v[c] + 1e-5f);
        const float sh = bb[c] - m[c] * s;
        acc += w1[(size_t)(o * 128 + c) * 9 + qj] * sh;
      }
      v1 = f2bf(acc);
    }
    wb1[i] = v1; wb2[i] = v2;
  }
  if (i < 32 * KT2) {               // offset/mask, NT=2
    const int j = i & 7, lane = (i >> 3) & 63, ot = (i >> 9) & 1, ch = i >> 10;
    const int o = ot * 16 + (lane & 15);
    const int qj = ((lane >> 4) << 3) + j;
    unsigned short v1 = 0, v2 = 0;
    if (ch < 36) {
      const int tap = ch >> 2;
      const int c   = ((ch & 3) << 5) + qj;
      const float s = g[c] * rsqrtf(v[c] + 1e-5f);
      if (o < 18) {
        v1 = f2bf(ow1[(size_t)(o * 128 + c) * 9 + tap] * s);
        v2 = f2bf(ow2[(size_t)(o * 128 + c) * 9 + tap]);
      } else if (o < 27) {
        v1 = f2bf(mw1[(size_t)((o - 18) * 128 + c) * 9 + tap] * s);
        v2 = f2bf(mw2[(size_t)((o - 18) * 128 + c) * 9 + tap]);
      }
    } else if (qj < KK && o < 27) {
      const float* wsrc = (o < 18) ? ow1 + (size_t)o * 1152
                                   : mw1 + (size_t)(o - 18) * 1152;
      float acc = 0.f;
      for (int c = 0; c < 128; ++c) {
        const float s  = g[c] * rsqrtf(v[c] + 1e-5f);
        const float sh = bb[c] - m[c] * s;
        acc += wsrc[(size_t)c * 9 + qj] * sh;
      }
      v1 = f2bf(acc);
    }
    wom1[i] = v1; wom2[i] = v2;
  }
  if (i < 32) {
    float b1 = 0.f, b2 = 0.f;
    if (i < 18)      { b1 = ob1[i];      b2 = ob2[i]; }
    else if (i < 27) { b1 = mb1[i - 18]; b2 = mb2[i - 18]; }
    bias1[i] = b1; bias2[i] = b2;
  }
}

extern "C" void kernel_launch(void* const* d_in, const int* in_sizes, int n_in,
                              void* d_out, int out_size, void* d_ws, size_t ws_size,
                              hipStream_t stream)
{
  const float* x     = (const float*)d_in[0];
  const float* bn1g  = (const float*)d_in[1];
  const float* bn1b  = (const float*)d_in[2];
  const float* bn1m  = (const float*)d_in[3];
  const float* bn1v  = (const float*)d_in[4];
  const float* ow1   = (const float*)d_in[5];
  const float* ob1   = (const float*)d_in[6];
  const float* mw1   = (const float*)d_in[7];
  const float* mb1   = (const float*)d_in[8];
  const float* w1    = (const float*)d_in[9];
  const float* alpha = (const float*)d_in[10];
  const float* ow2   = (const float*)d_in[11];
  const float* ob2   = (const float*)d_in[12];
  const float* mw2   = (const float*)d_in[13];
  const float* mb2   = (const float*)d_in[14];
  const float* w2    = (const float*)d_in[15];
  const float* bn2g  = (const float*)d_in[16];
  const float* bn2b  = (const float*)d_in[17];
  const float* bn2m  = (const float*)d_in[18];
  const float* bn2v  = (const float*)d_in[19];
  float* out = (float*)d_out;

  char* wsp = (char*)d_ws;
  unsigned short* xbf  = (unsigned short*)(wsp);             // NHWC bf16
  unsigned short* r2bf = (unsigned short*)(wsp + 16777216);  // NHWC bf16
  unsigned short* wb1  = (unsigned short*)(wsp + 40632320);  // 303104
  unsigned short* wb2  = (unsigned short*)(wsp + 40935424);  // 303104
  unsigned short* wom1 = (unsigned short*)(wsp + 41238528);  // 75776
  unsigned short* wom2 = (unsigned short*)(wsp + 41314304);  // 75776
  float* bias1 = (float*)(wsp + 41390080);
  float* bias2 = (float*)(wsp + 41390208);

  xcvt3<<<dim3(256, 4), 256, 0, stream>>>(x, xbf);
  prep5<<<(128 * KT2 + 255) / 256, 256, 0, stream>>>(
      w1, w2, ow1, mw1, ob1, mb1, ow2, mw2, ob2, mb2,
      bn1g, bn1b, bn1m, bn1v, wb1, wb2, wom1, wom2, bias1, bias2);

  fusedL<1><<<1024, 256, 0, stream>>>(xbf, wom1, wb1, bias1, alpha,
      nullptr, nullptr, nullptr, nullptr, r2bf, nullptr);
  fusedL<2><<<1024, 256, 0, stream>>>(r2bf, wom2, wb2, bias2, bn2g,
      bn2b, bn2m, bn2v, x, nullptr, out);
}

// Round 3
// 337.890 us; speedup vs baseline: 1.1303x; 1.0189x over previous
//
#include <hip/hip_runtime.h>
#include <hip/hip_bf16.h>
#include <hip/hip_fp16.h>
#include <math.h>

#define DEV_INLINE __device__ __forceinline__

typedef __attribute__((ext_vector_type(8))) short short8;
typedef __attribute__((ext_vector_type(8))) unsigned short ushort8v;
typedef __attribute__((ext_vector_type(4))) float f32x4;

constexpr int H = 128, W = 128, C = 128, B = 4;
constexpr int KK = 9;
constexpr int KT2 = 1184;         // 37 chunks * 32

DEV_INLINE unsigned short f2bf(float f) {
  union { float f; unsigned u; } v; v.f = f;
  unsigned r = v.u + 0x7FFFu + ((v.u >> 16) & 1u);   // RNE
  return (unsigned short)(r >> 16);
}
DEV_INLINE float ubits(unsigned u) {
  union { unsigned u; float f; } v; v.u = u; return v.f;
}
DEV_INLINE float bfu(unsigned short u) { return ubits(((unsigned)u) << 16); }
DEV_INLINE unsigned pack2bf(float a, float b) {
  float2 t; t.x = a; t.y = b;
  __hip_bfloat162 h = __float22bfloat162_rn(t);
  union { __hip_bfloat162 h; unsigned u; } c; c.h = h;
  return c.u;
}
DEV_INLINE unsigned f2h2(float a, float b) {
  __half2 h = __floats2half2_rn(a, b);
  union { __half2 h; unsigned u; } c; c.h = h;
  return c.u;
}
DEV_INLINE float2 h2f2(unsigned u) {
  union { unsigned u; __half2 h; } c; c.u = u;
  return __half22float2(c.h);
}
// async global->LDS, 16B per lane (wave-uniform LDS base + lane*16)
DEV_INLINE void gload_lds16(const unsigned short* g, unsigned short* l) {
  __builtin_amdgcn_global_load_lds(
      (const __attribute__((address_space(1))) unsigned*)g,
      (__attribute__((address_space(3))) unsigned*)l, 16, 0, 0);
}

// Fully fused deform layer over NHWC bf16: per block (64 positions = one
// 64-px row segment, 4 waves x 16 pos, full K).
//
// ROUND-3 STRUCTURE CHANGE: rounds 0-2 fully unrolled the 36-chunk phase-1 and
// phase-3 loops -> ~55-60 KB straight-line body. All three memory-schedule
// variants landed at 120-137 us with MfmaUtil ~8% / VALUBusy ~25% and every
// pipe idle => instruction-FETCH bound (4 waves streaming a body 2x the 32 KB
// I-cache, no reuse). This version ROLLS the loops so the hot code (~5 KB) is
// I-cache resident and shared by all co-resident waves:
//   Phase 1: rolled over ch (runtime), 1-ahead prefetch of wOM + src in
//            static register slots.
//   Phase 2: per-lane bilinear table -> sTab LDS [9 taps][64 pos] as uint4
//            {rowpair id, fp16 w01, fp16 w23, pad} (q==0 lanes write).
//   Phase 3: rolled over tap (9 iters), cg unrolled x4 inside so pipeline
//            slot indices stay compile-time. Per tap one ds_read_b128 pulls
//            the table entry (broadcast across q); next tap's entry
//            prefetched at cg==2. Counted-vmcnt schedule as round 2:
//            stage ch+1 via global_load_lds -> blend ch -> 8 MFMA ->
//            issue gathers ch+2 -> s_waitcnt vmcnt(4) + s_barrier.
// Chunk ch<36: tap=ch>>2, cg=ch&3, k=q*8+j -> channel cg*32+q*8+j at tap.
// LAYER 1 (BN): +chunk 36 (A rows = BN1-shift cols; B = wt-sum / validity,
//   precomputed into 4 regs before the loop); epilogue PReLU -> NHWC bf16.
// LAYER 2: 36 chunks; BN2 + NCHW residual.
template<int LAYER>
__global__ __launch_bounds__(256, 4)
void fusedL(const unsigned short* __restrict__ src,     // NHWC bf16
            const unsigned short* __restrict__ wOM,     // [37][2][64][8]
            const unsigned short* __restrict__ wS,      // [37][8][64][8]
            const float* __restrict__ bias,             // [32]
            const float* __restrict__ pA, const float* __restrict__ pB,
            const float* __restrict__ pM, const float* __restrict__ pV,
            const float* __restrict__ resid,
            unsigned short* __restrict__ outh,          // LAYER1 NHWC bf16
            float* __restrict__ outf)                   // LAYER2 NCHW fp32
{
  constexpr bool BN   = (LAYER == 1);
  constexpr int  NCH3 = BN ? 37 : 36;
  __shared__ __attribute__((aligned(16))) char smem[16384 + 9216];
  float* sOff = (float*)smem;                            // [64][29] = 7424 B
  unsigned short* aBuf0 = (unsigned short*)smem;         // 8 KB (overlays sOff)
  unsigned short* aBuf1 = (unsigned short*)(smem + 8192);
  unsigned* sTab = (unsigned*)(smem + 16384);            // [9][64] uint4

  const int tid  = threadIdx.x;
  const int lane = tid & 63;
  const int m16  = lane & 15;
  const int q    = lane >> 4;
  const int wv   = tid >> 6;

  const int raw  = blockIdx.x;                // 1024 blocks
  const int xcd  = raw & 7;
  const int slot = raw >> 3;                  // [0,128)
  const int b    = xcd >> 1;
  const int hy   = ((xcd & 1) << 6) | (slot >> 1);
  const int hx0  = (slot & 1) << 6;           // 64-wide segment
  const unsigned short* __restrict__ srcB = src + ((size_t)b << 14) * C;

  const int pos = (wv << 4) + m16;            // block-local position
  const int hx  = hx0 + pos;
  const int cbq = q << 3;

  // ================= Phase 1: offset/mask conv (rolled, prefetched) ========
  f32x4 acc2[2];
  acc2[0] = (f32x4){0.f, 0.f, 0.f, 0.f};
  acc2[1] = (f32x4){0.f, 0.f, 0.f, 0.f};

  ushort8v pv;
  bool pvok;
  {
    const int iy = hy - 1, ix = hx - 1;       // ch=0: tap 0 (ky=0,kx=0), cg=0
    pvok = ((unsigned)iy < (unsigned)H) && ((unsigned)ix < (unsigned)W);
    const int rb = pvok ? (iy * W + ix) : 0;
    pv = *(const ushort8v*)(srcB + ((size_t)rb * C + cbq));
  }
  short8 pa0 = *(const short8*)(wOM + (size_t)lane * 8);
  short8 pa1 = *(const short8*)(wOM + (size_t)lane * 8 + 512);

  #pragma unroll 1
  for (int ch = 0; ch < 36; ++ch) {
    const short8 a0 = pa0, a1 = pa1;
    if (ch + 1 < 36) {                         // weight prefetch (L2-hot)
      const unsigned short* ap = wOM + ((size_t)((ch + 1) * 128 + lane)) * 8;
      pa0 = *(const short8*)(ap);
      pa1 = *(const short8*)(ap + 512);
    }
    ushort8v nv = pv;
    bool nok = false;
    if (ch + 1 < 36) {                         // source prefetch
      const int tapn = (ch + 1) >> 2, cgn = (ch + 1) & 3;
      const int ky = tapn / 3, kx = tapn - 3 * (tapn / 3);
      const int iy = hy + ky - 1;
      const int ix = hx + kx - 1;
      nok = ((unsigned)iy < (unsigned)H) && ((unsigned)ix < (unsigned)W);
      const int rb = nok ? (iy * W + ix) : 0;
      nv = *(const ushort8v*)(srcB + ((size_t)rb * C + (cgn << 5) + cbq));
    }
    union { ushort8v v; unsigned u[4]; short8 s; } bfr;
    bfr.v = pv;
    if (!pvok) { bfr.u[0] = 0; bfr.u[1] = 0; bfr.u[2] = 0; bfr.u[3] = 0; }
    acc2[0] = __builtin_amdgcn_mfma_f32_16x16x32_bf16(a0, bfr.s, acc2[0], 0, 0, 0);
    acc2[1] = __builtin_amdgcn_mfma_f32_16x16x32_bf16(a1, bfr.s, acc2[1], 0, 0, 0);
    pv = nv; pvok = nok;
  }
  if constexpr (BN) {   // validity column chunk
    union { unsigned u[4]; short8 s; } bfr;
    float sv[8];
    #pragma unroll
    for (int j = 0; j < 8; ++j) {
      const int kj = cbq + j;
      float s = 0.f;
      if (kj < KK) {
        const int ky = kj / 3, kx = kj - 3 * (kj / 3);
        const int iy = hy + ky - 1, ix = hx + kx - 1;
        s = (((unsigned)iy < (unsigned)H) && ((unsigned)ix < (unsigned)W)) ? 1.f : 0.f;
      }
      sv[j] = s;
    }
    #pragma unroll
    for (int t = 0; t < 4; ++t) bfr.u[t] = pack2bf(sv[2 * t], sv[2 * t + 1]);
    const unsigned short* ap = wOM + ((size_t)36 * 128 + lane) * 8;
    acc2[0] = __builtin_amdgcn_mfma_f32_16x16x32_bf16(*(const short8*)(ap), bfr.s, acc2[0], 0, 0, 0);
    acc2[1] = __builtin_amdgcn_mfma_f32_16x16x32_bf16(*(const short8*)(ap + 512), bfr.s, acc2[1], 0, 0, 0);
  }
  // epilogue -> sOff (D col = m16 -> pos, row = q*4+rg -> o)
  #pragma unroll
  for (int ot = 0; ot < 2; ++ot) {
    #pragma unroll
    for (int rg = 0; rg < 4; ++rg) {
      const int o = ot * 16 + (q << 2) + rg;
      if (o < 27) {
        float v = acc2[ot][rg] + bias[o];
        if (o >= 18) v = 2.f / (1.f + expf(-v));
        sOff[pos * 29 + o] = v;
      }
    }
  }
  __syncthreads();

  // ================= Phase 2: bilinear table -> sTab LDS ===================
  unsigned bnB0 = 0, bnB1 = 0, bnB2 = 0, bnB3 = 0;   // BN chunk B-frag (L1)
  {
    unsigned tId[9], tW01[9], tW23[9];
    const float* myOff = sOff + pos * 29;
    #pragma unroll
    for (int tap = 0; tap < 9; ++tap) {
      const int ky = tap / 3, kx = tap - 3 * (tap / 3);
      const float oy = myOff[2 * tap];
      const float ox = myOff[2 * tap + 1];
      const float mv = myOff[18 + tap];
      const float py = (float)(hy - 1 + ky) + oy;
      const float px = (float)(hx - 1 + kx) + ox;
      const float fy = floorf(py), fx = floorf(px);
      const float ay = py - fy, ax = px - fx;
      const int y0 = (int)fy, x0 = (int)fx;
      const int y1 = y0 + 1, x1 = x0 + 1;
      const float wyt = (1.f - ay) * (((unsigned)y0 < (unsigned)H) ? 1.f : 0.f);
      const float wyb = ay * (((unsigned)y1 < (unsigned)H) ? 1.f : 0.f);
      const int y0c = min(max(y0, 0), H - 1), y1c = min(max(y1, 0), H - 1);
      const int bx  = min(max(x0, 0), W - 2);
      float wA = 0.f, wB = 0.f;
      if (x0 == bx)          { wA = 1.f - ax; wB = ax; }
      else if (x1 == bx)     { wA = ax; }
      else if (x0 == bx + 1) { wB = 1.f - ax; }
      tId[tap]  = (unsigned)(y0c * W + bx) | ((unsigned)(y1c * W + bx) << 16);
      tW01[tap] = f2h2(mv * wyt * wA, mv * wyt * wB);
      tW23[tap] = f2h2(mv * wyb * wA, mv * wyb * wB);
    }
    if (q == 0) {     // all q computed identical tables; one writer per pos
      #pragma unroll
      for (int tap = 0; tap < 9; ++tap) {
        uint4 e;
        e.x = tId[tap]; e.y = tW01[tap]; e.z = tW23[tap]; e.w = 0u;
        *(uint4*)(sTab + ((size_t)(tap * 64 + pos)) * 4) = e;
      }
    }
    if constexpr (BN) {  // precompute BN-column B fragment (4 regs)
      float sv[8];
      if (q == 0) {
        #pragma unroll
        for (int j = 0; j < 8; ++j) {
          const float2 a = h2f2(tW01[j]);
          const float2 c = h2f2(tW23[j]);
          sv[j] = a.x + a.y + c.x + c.y;
        }
      } else if (q == 1) {
        const float2 a = h2f2(tW01[8]);
        const float2 c = h2f2(tW23[8]);
        sv[0] = a.x + a.y + c.x + c.y;
        #pragma unroll
        for (int j = 1; j < 8; ++j) sv[j] = 0.f;
      } else {
        #pragma unroll
        for (int j = 0; j < 8; ++j) sv[j] = 0.f;
      }
      bnB0 = pack2bf(sv[0], sv[1]); bnB1 = pack2bf(sv[2], sv[3]);
      bnB2 = pack2bf(sv[4], sv[5]); bnB3 = pack2bf(sv[6], sv[7]);
    }
  }
  __syncthreads();   // sOff dead + sTab visible; aBuf0 may now be written

  // ================= Phase 3: deform GEMM (rolled, counted-vmcnt) ==========
  f32x4 acc[8];
  #pragma unroll
  for (int i = 0; i < 8; ++i) acc[i] = (f32x4){0.f, 0.f, 0.f, 0.f};

  ushort8v gTL[2], gTR[2], gBL[2], gBR[2];   // depth-2 gather pipeline

  // prologue: stage chunk 0 weights, tap-0 table entry, gathers chunks 0,1
  {
    unsigned short* dst0 = aBuf0 + (wv << 9);        // wave-uniform base
    gload_lds16(wS + (size_t)tid * 8, dst0);
    gload_lds16(wS + (size_t)(256 + tid) * 8, dst0 + 2048);
  }
  asm volatile("" ::: "memory");   // staging issued before gathers (vmcnt order)
  uint4 tab = *(const uint4*)(sTab + (size_t)pos * 4);
  unsigned tIdC = tab.x, wPk01 = tab.y, wPk23 = tab.z;
  #pragma unroll
  for (int pc = 0; pc < 2; ++pc) {
    const int cbase = (pc << 5) + cbq;
    const unsigned short* pT  = srcB + ((size_t)(tIdC & 0xFFFFu) * C + cbase);
    const unsigned short* pBt = srcB + ((size_t)(tIdC >> 16) * C + cbase);
    gTL[pc] = *(const ushort8v*)(pT);
    gTR[pc] = *(const ushort8v*)(pT + C);
    gBL[pc] = *(const ushort8v*)(pBt);
    gBR[pc] = *(const ushort8v*)(pBt + C);
  }
  asm volatile("s_waitcnt vmcnt(8)" ::: "memory");   // staging(0) retired
  __builtin_amdgcn_s_barrier();
  __builtin_amdgcn_sched_barrier(0);

  unsigned tIdN = tIdC, nPk01 = wPk01, nPk23 = wPk23;
  #pragma unroll 1
  for (int tap = 0; tap < 9; ++tap) {
    #pragma unroll
    for (int cg = 0; cg < 4; ++cg) {
      const int ch = (tap << 2) + cg;
      // ---- stage next chunk's weights (async, to the other buffer) ----
      if (ch + 1 < NCH3) {
        unsigned short* wd = ((cg + 1) & 1) ? aBuf1 : aBuf0;
        unsigned short* dst = wd + (wv << 9);
        const size_t gb = (size_t)(ch + 1) * 4096;
        gload_lds16(wS + gb + (size_t)tid * 8, dst);
        gload_lds16(wS + gb + (size_t)(256 + tid) * 8, dst + 2048);
      }
      asm volatile("" ::: "memory");   // pin staging before this iter's gathers

      // ---- prefetch next tap's table entry (used for cg>=2 gathers) ----
      if (cg == 2 && tap < 8) {
        uint4 tn = *(const uint4*)(sTab + ((size_t)((tap + 1) * 64 + pos)) * 4);
        tIdN = tn.x; nPk01 = tn.y; nPk23 = tn.z;
      }

      // ---- blend current gathers -> B fragment ----
      const float2 w01 = h2f2(wPk01);
      const float2 w23 = h2f2(wPk23);
      const ushort8v TL = gTL[cg & 1], TR = gTR[cg & 1];
      const ushort8v BL = gBL[cg & 1], BR = gBR[cg & 1];
      union { unsigned u[4]; short8 s; } bfr;
      #pragma unroll
      for (int t = 0; t < 4; ++t) {
        const float sv0 = w01.x * bfu(TL[2 * t])     + w01.y * bfu(TR[2 * t])
                        + w23.x * bfu(BL[2 * t])     + w23.y * bfu(BR[2 * t]);
        const float sv1 = w01.x * bfu(TL[2 * t + 1]) + w01.y * bfu(TR[2 * t + 1])
                        + w23.x * bfu(BL[2 * t + 1]) + w23.y * bfu(BR[2 * t + 1]);
        bfr.u[t] = pack2bf(sv0, sv1);
      }

      // ---- A-fragments from LDS + MFMA ----
      const unsigned short* rbuf = (cg & 1) ? aBuf1 : aBuf0;
      #pragma unroll
      for (int ot = 0; ot < 8; ++ot) {
        const short8 afr = *(const short8*)(rbuf + ((size_t)(ot * 64 + lane)) * 8);
        acc[ot] = __builtin_amdgcn_mfma_f32_16x16x32_bf16(afr, bfr.s, acc[ot], 0, 0, 0);
      }

      // ---- issue gathers for chunk ch+2 (consumed 2 chunks later) ----
      if (ch + 2 < 36) {
        const unsigned idp = (cg < 2) ? tIdC : tIdN;
        const int cbase = (((cg + 2) & 3) << 5) + cbq;
        const unsigned short* pT  = srcB + ((size_t)(idp & 0xFFFFu) * C + cbase);
        const unsigned short* pBt = srcB + ((size_t)(idp >> 16) * C + cbase);
        gTL[cg & 1] = *(const ushort8v*)(pT);
        gTR[cg & 1] = *(const ushort8v*)(pT + C);
        gBL[cg & 1] = *(const ushort8v*)(pBt);
        gBR[cg & 1] = *(const ushort8v*)(pBt + C);
      }

      // ---- counted wait: staging retired, newest gathers stay in flight ----
      if (ch + 1 < NCH3) {
        asm volatile("s_waitcnt vmcnt(4)" ::: "memory");
        __builtin_amdgcn_s_barrier();
        __builtin_amdgcn_sched_barrier(0);
      }
    }
    tIdC = tIdN; wPk01 = nPk01; wPk23 = nPk23;   // rotate to next tap
  }

  if constexpr (BN) {   // chunk 36: BN-shift column (B-frag precomputed)
    asm volatile("s_waitcnt vmcnt(0)" ::: "memory");   // chunk-36 staging done
    __builtin_amdgcn_s_barrier();
    union { unsigned u[4]; short8 s; } bfr;
    bfr.u[0] = bnB0; bfr.u[1] = bnB1; bfr.u[2] = bnB2; bfr.u[3] = bnB3;
    #pragma unroll
    for (int ot = 0; ot < 8; ++ot) {
      const short8 afr = *(const short8*)(aBuf0 + ((size_t)(ot * 64 + lane)) * 8);
      acc[ot] = __builtin_amdgcn_mfma_f32_16x16x32_bf16(afr, bfr.s, acc[ot], 0, 0, 0);
    }
  }

  // ---- epilogue ----
  #pragma unroll
  for (int ot = 0; ot < 8; ++ot) {
    if constexpr (LAYER == 1) {
      const float a0 = pA[ot * 16 + (q << 2) + 0];
      const float a1 = pA[ot * 16 + (q << 2) + 1];
      const float a2 = pA[ot * 16 + (q << 2) + 2];
      const float a3 = pA[ot * 16 + (q << 2) + 3];
      const float v0 = acc[ot][0], v1 = acc[ot][1];
      const float v2 = acc[ot][2], v3 = acc[ot][3];
      uint2 st;
      st.x = pack2bf(v0 > 0.f ? v0 : a0 * v0, v1 > 0.f ? v1 : a1 * v1);
      st.y = pack2bf(v2 > 0.f ? v2 : a2 * v2, v3 > 0.f ? v3 : a3 * v3);
      const int n = (b << 14) + hy * W + hx;
      *(uint2*)(outh + (size_t)n * C + ot * 16 + (q << 2)) = st;
    } else {
      #pragma unroll
      for (int rg = 0; rg < 4; ++rg) {
        const int o = ot * 16 + (q << 2) + rg;
        const float vv = acc[ot][rg];
        const size_t oi = (((size_t)(b * C + o)) << 14) + hy * W + hx;
        const float s  = pA[o] * rsqrtf(pV[o] + 1e-5f);
        const float sh = pB[o] - pM[o] * s;
        outf[oi] = vv * s + sh + resid[oi];
      }
    }
  }
}

// NCHW fp32 -> NHWC bf16, LDS-tiled (coalesced loads AND stores)
__global__ __launch_bounds__(256, 4)
void xcvt3(const float* __restrict__ x, unsigned short* __restrict__ xb)
{
  __shared__ unsigned tile[64 * 69];
  const int b   = blockIdx.y;
  const int p0  = blockIdx.x * 64;
  const int tid = threadIdx.x;
  const int pl  = tid & 63;
  const int cg  = tid >> 6;
  const float* __restrict__ xp = x + (((size_t)(b * C) + cg * 32) << 14) + p0 + pl;
  #pragma unroll
  for (int j = 0; j < 16; ++j) {
    const float a = xp[(size_t)(2 * j) << 14];
    const float c = xp[(size_t)(2 * j + 1) << 14];
    tile[pl * 69 + cg * 16 + j] = pack2bf(a, c);
  }
  __syncthreads();
  const int pl2 = tid >> 2;
  const int cq  = tid & 3;
  unsigned* dst = (unsigned*)(xb + (((size_t)(b << 14)) + p0 + pl2) * C + cq * 32);
  #pragma unroll
  for (int k = 0; k < 16; k += 4) {
    uint4 v;
    v.x = tile[pl2 * 69 + cq * 16 + k];
    v.y = tile[pl2 * 69 + cq * 16 + k + 1];
    v.z = tile[pl2 * 69 + cq * 16 + k + 2];
    v.w = tile[pl2 * 69 + cq * 16 + k + 3];
    *(uint4*)(dst + k) = v;
  }
}

// Swizzled weights, tap-major chunks: wS[((ch*NT+ot)*64+lane)*8+j] =
// w[o=ot*16+(lane&15)][c=(ch&3)*32+(lane>>4)*8+j][tap=ch>>2] (ch<36);
// ch==36: BN-shift col (kj=(lane>>4)*8+j < 9), layer-1 only.
__global__ void prep5(const float* __restrict__ w1, const float* __restrict__ w2,
                      const float* __restrict__ ow1, const float* __restrict__ mw1,
                      const float* __restrict__ ob1, const float* __restrict__ mb1,
                      const float* __restrict__ ow2, const float* __restrict__ mw2,
                      const float* __restrict__ ob2, const float* __restrict__ mb2,
                      const float* __restrict__ g, const float* __restrict__ bb,
                      const float* __restrict__ m, const float* __restrict__ v,
                      unsigned short* __restrict__ wb1, unsigned short* __restrict__ wb2,
                      unsigned short* __restrict__ wom1, unsigned short* __restrict__ wom2,
                      float* __restrict__ bias1, float* __restrict__ bias2)
{
  const int i = blockIdx.x * 256 + threadIdx.x;
  if (i < 128 * KT2) {              // deform, NT=8
    const int j = i & 7, lane = (i >> 3) & 63, ot = (i >> 9) & 7, ch = i >> 12;
    const int o = ot * 16 + (lane & 15);
    const int qj = ((lane >> 4) << 3) + j;
    unsigned short v1 = 0, v2 = 0;
    if (ch < 36) {
      const int tap = ch >> 2;
      const int c   = ((ch & 3) << 5) + qj;
      const float s = g[c] * rsqrtf(v[c] + 1e-5f);
      v1 = f2bf(w1[(size_t)(o * 128 + c) * 9 + tap] * s);
      v2 = f2bf(w2[(size_t)(o * 128 + c) * 9 + tap]);
    } else if (qj < KK) {
      float acc = 0.f;
      for (int c = 0; c < 128; ++c) {
        const float s  = g[c] * rsqrtf(v[c] + 1e-5f);
        const float sh = bb[c] - m[c] * s;
        acc += w1[(size_t)(o * 128 + c) * 9 + qj] * sh;
      }
      v1 = f2bf(acc);
    }
    wb1[i] = v1; wb2[i] = v2;
  }
  if (i < 32 * KT2) {               // offset/mask, NT=2
    const int j = i & 7, lane = (i >> 3) & 63, ot = (i >> 9) & 1, ch = i >> 10;
    const int o = ot * 16 + (lane & 15);
    const int qj = ((lane >> 4) << 3) + j;
    unsigned short v1 = 0, v2 = 0;
    if (ch < 36) {
      const int tap = ch >> 2;
      const int c   = ((ch & 3) << 5) + qj;
      const float s = g[c] * rsqrtf(v[c] + 1e-5f);
      if (o < 18) {
        v1 = f2bf(ow1[(size_t)(o * 128 + c) * 9 + tap] * s);
        v2 = f2bf(ow2[(size_t)(o * 128 + c) * 9 + tap]);
      } else if (o < 27) {
        v1 = f2bf(mw1[(size_t)((o - 18) * 128 + c) * 9 + tap] * s);
        v2 = f2bf(mw2[(size_t)((o - 18) * 128 + c) * 9 + tap]);
      }
    } else if (qj < KK && o < 27) {
      const float* wsrc = (o < 18) ? ow1 + (size_t)o * 1152
                                   : mw1 + (size_t)(o - 18) * 1152;
      float acc = 0.f;
      for (int c = 0; c < 128; ++c) {
        const float s  = g[c] * rsqrtf(v[c] + 1e-5f);
        const float sh = bb[c] - m[c] * s;
        acc += wsrc[(size_t)c * 9 + qj] * sh;
      }
      v1 = f2bf(acc);
    }
    wom1[i] = v1; wom2[i] = v2;
  }
  if (i < 32) {
    float b1 = 0.f, b2 = 0.f;
    if (i < 18)      { b1 = ob1[i];      b2 = ob2[i]; }
    else if (i < 27) { b1 = mb1[i - 18]; b2 = mb2[i - 18]; }
    bias1[i] = b1; bias2[i] = b2;
  }
}

extern "C" void kernel_launch(void* const* d_in, const int* in_sizes, int n_in,
                              void* d_out, int out_size, void* d_ws, size_t ws_size,
                              hipStream_t stream)
{
  const float* x     = (const float*)d_in[0];
  const float* bn1g  = (const float*)d_in[1];
  const float* bn1b  = (const float*)d_in[2];
  const float* bn1m  = (const float*)d_in[3];
  const float* bn1v  = (const float*)d_in[4];
  const float* ow1   = (const float*)d_in[5];
  const float* ob1   = (const float*)d_in[6];
  const float* mw1   = (const float*)d_in[7];
  const float* mb1   = (const float*)d_in[8];
  const float* w1    = (const float*)d_in[9];
  const float* alpha = (const float*)d_in[10];
  const float* ow2   = (const float*)d_in[11];
  const float* ob2   = (const float*)d_in[12];
  const float* mw2   = (const float*)d_in[13];
  const float* mb2   = (const float*)d_in[14];
  const float* w2    = (const float*)d_in[15];
  const float* bn2g  = (const float*)d_in[16];
  const float* bn2b  = (const float*)d_in[17];
  const float* bn2m  = (const float*)d_in[18];
  const float* bn2v  = (const float*)d_in[19];
  float* out = (float*)d_out;

  char* wsp = (char*)d_ws;
  unsigned short* xbf  = (unsigned short*)(wsp);             // NHWC bf16
  unsigned short* r2bf = (unsigned short*)(wsp + 16777216);  // NHWC bf16
  unsigned short* wb1  = (unsigned short*)(wsp + 40632320);  // 303104
  unsigned short* wb2  = (unsigned short*)(wsp + 40935424);  // 303104
  unsigned short* wom1 = (unsigned short*)(wsp + 41238528);  // 75776
  unsigned short* wom2 = (unsigned short*)(wsp + 41314304);  // 75776
  float* bias1 = (float*)(wsp + 41390080);
  float* bias2 = (float*)(wsp + 41390208);

  xcvt3<<<dim3(256, 4), 256, 0, stream>>>(x, xbf);
  prep5<<<(128 * KT2 + 255) / 256, 256, 0, stream>>>(
      w1, w2, ow1, mw1, ob1, mb1, ow2, mw2, ob2, mb2,
      bn1g, bn1b, bn1m, bn1v, wb1, wb2, wom1, wom2, bias1, bias2);

  fusedL<1><<<1024, 256, 0, stream>>>(xbf, wom1, wb1, bias1, alpha,
      nullptr, nullptr, nullptr, nullptr, r2bf, nullptr);
  fusedL<2><<<1024, 256, 0, stream>>>(r2bf, wom2, wb2, bias2, bn2g,
      bn2b, bn2m, bn2v, x, nullptr, out);
}